// Round 8
// baseline (204.880 us; speedup 1.0000x reference)
//
#include <hip/hip_runtime.h>

#define NP 8732
#define NQ (NP / 4)          // 2183 float4 chunks
#define NO 16
#define BLK 256
#define NWAVE (BLK / 64)
#define SPLIT 4
#define CHUNK (NP / SPLIT)   // 2183 exactly
#define CAP 4096             // candidate LDS capacity in select_kernel

// ---------------------------------------------------------------------------
// Evidence log:
//  - One block/row = 2 blocks/CU (21% occ): latency-bound. Split phases.
//  - launch_bounds waves/EU too high parks arrays in AGPRs (unified file):
//    (256,8) -> VGPR 32 + accvgpr traffic, VALU-bound at 87%. Use (256,4)
//    for kernels with per-thread arrays. Cap below need spills (52MB scratch).
//  - BLK=512 regressed (barrier pile-up).
//  - loss_kernel (grid B) was 13% VALU / 20% occ: serial select chain.
//    Round 8: CE+hist at grid BxSPLIT -> global hist; slim per-row select.
// ---------------------------------------------------------------------------

// Kernel A: match a CHUNK of priors vs all 16 objects. Lane quads own 4
// objects each; 64 priors per wave-iteration.
__global__ __launch_bounds__(BLK, 4) void match_kernel(
    const float* __restrict__ boxes,    // [B,O,4] cxcy
    const float* __restrict__ priors,   // [P,4]  cxcy
    unsigned char* __restrict__ g_obj,  // [B,NP]
    float* __restrict__ g_bv,           // [B,16,SPLIT]
    int*   __restrict__ g_bi)           // [B,16,SPLIT]
{
    const int b    = blockIdx.x;
    const int s    = blockIdx.y;
    const int tid  = threadIdx.x;
    const int lane = tid & 63;
    const int wv   = tid >> 6;
    const int quad = tid & 3;
    const int objLo = quad << 2;
    const int lo = s * CHUNK, hi = lo + CHUNK;

    __shared__ float s_bxy[NO][4];
    __shared__ float s_barea[NO];
    __shared__ float s_redv[NO * NWAVE];
    __shared__ int   s_redi[NO * NWAVE];

    if (tid < NO) {
        const float* bx = boxes + (size_t)b * NO * 4 + tid * 4;
        float cx = bx[0], cy = bx[1], w = bx[2], h = bx[3];
        s_bxy[tid][0] = cx - w * 0.5f; s_bxy[tid][1] = cy - h * 0.5f;
        s_bxy[tid][2] = cx + w * 0.5f; s_bxy[tid][3] = cy + h * 0.5f;
        s_barea[tid] = w * h;
    }
    __syncthreads();

    float rx0[4], ry0[4], rx1[4], ry1[4], ra[4];
#pragma unroll
    for (int j = 0; j < 4; j++) {
        rx0[j] = s_bxy[objLo + j][0]; ry0[j] = s_bxy[objLo + j][1];
        rx1[j] = s_bxy[objLo + j][2]; ry1[j] = s_bxy[objLo + j][3];
        ra[j]  = s_barea[objLo + j];
    }

    float tbv[4]; int tbp[4];
#pragma unroll
    for (int j = 0; j < 4; j++) { tbv[j] = -1.0f; tbp[j] = lo; }

    unsigned char* obj_row = g_obj + (size_t)b * NP;
    for (int p = lo + (tid >> 2); p < hi; p += (BLK / 4)) {
        float4 pr = ((const float4*)priors)[p];
        float px0 = pr.x - pr.z * 0.5f, py0 = pr.y - pr.w * 0.5f;
        float px1 = pr.x + pr.z * 0.5f, py1 = pr.y + pr.w * 0.5f;
        float areab = pr.z * pr.w;
        float bv = -1.0f; int bo = objLo;
#pragma unroll
        for (int j = 0; j < 4; j++) {
            float ix0 = fmaxf(rx0[j], px0);
            float iy0 = fmaxf(ry0[j], py0);
            float ix1 = fminf(rx1[j], px1);
            float iy1 = fminf(ry1[j], py1);
            float iw = fmaxf(ix1 - ix0, 0.0f);
            float ih = fmaxf(iy1 - iy0, 0.0f);
            float inter = iw * ih;
            float den = ra[j] + areab - inter;
            float iou = inter * __builtin_amdgcn_rcpf(den);
            if (iou > bv)     { bv = iou; bo = objLo + j; }
            if (iou > tbv[j]) { tbv[j] = iou; tbp[j] = p; }
        }
        // combine across the quad; lower lane = lower object indices wins ties
        float vN = __shfl_xor(bv, 1, 64);
        int   oN = __shfl_xor(bo, 1, 64);
        bool take = (quad & 1) ? (vN >= bv) : (vN > bv);
        if (take) { bv = vN; bo = oN; }
        vN = __shfl_xor(bv, 2, 64);
        oN = __shfl_xor(bo, 2, 64);
        take = (quad & 2) ? (vN >= bv) : (vN > bv);
        if (take) { bv = vN; bo = oN; }
        if (quad == 0) {
            bool pos = (bv >= 0.5f);
            obj_row[p] = (unsigned char)(bo | (pos ? 0x80 : 0));
        }
    }

#pragma unroll
    for (int j = 0; j < 4; j++) {
        float v = tbv[j]; int i = tbp[j];
        for (int off = 32; off >= 4; off >>= 1) {
            float v2 = __shfl_down(v, off, 64);
            int   i2 = __shfl_down(i, off, 64);
            if (v2 > v || (v2 == v && i2 < i)) { v = v2; i = i2; }
        }
        if (lane < 4) {
            s_redv[(objLo + j) * NWAVE + wv] = v;
            s_redi[(objLo + j) * NWAVE + wv] = i;
        }
    }
    __syncthreads();
    if (tid < NO) {
        float v = s_redv[tid * NWAVE]; int i = s_redi[tid * NWAVE];
#pragma unroll
        for (int w = 1; w < NWAVE; w++) {
            float v2 = s_redv[tid * NWAVE + w]; int i2 = s_redi[tid * NWAVE + w];
            if (v2 > v || (v2 == v && i2 < i)) { v = v2; i = i2; }
        }
        g_bv[((size_t)b * NO + tid) * SPLIT + s] = v;
        g_bi[((size_t)b * NO + tid) * SPLIT + s] = i;
    }
}

__global__ __launch_bounds__(BLK) void zero_hist_kernel(uint4* g, int n4) {
    int i = blockIdx.x * BLK + threadIdx.x;
    if (i < n4) g[i] = make_uint4(0u, 0u, 0u, 0u);
}

// Kernel B: CE + loc for a chunk; writes ce values, merges a per-row
// 4096-bin histogram (bits 30:19) into global, writes chunk partials.
__global__ __launch_bounds__(BLK, 4) void ce_kernel(
    const float* __restrict__ plocs,    // [B,P,4]
    const float* __restrict__ pscores,  // [B,P,2]
    const float* __restrict__ boxes,    // [B,O,4]
    const float* __restrict__ priors,   // [P,4]
    const unsigned char* __restrict__ g_obj,
    const float* __restrict__ g_bv,
    const int*   __restrict__ g_bi,
    float* __restrict__ g_ce,           // [B,NP]
    unsigned* __restrict__ g_hist,      // [B,4096]
    float* __restrict__ g_part)         // [B,SPLIT,4]: np,conf_pos,loc,ce_sum
{
    const int b    = blockIdx.x;
    const int s    = blockIdx.y;
    const int tid  = threadIdx.x;
    const int lane = tid & 63;
    const int wv   = tid >> 6;
    const int lo = s * CHUNK, hi = lo + CHUNK;

    __shared__ unsigned char s_objc[CHUNK];
    __shared__ float s_bcw[NO][4];
    __shared__ int   s_bestp[NO];
    __shared__ unsigned s_hist[4096];
    __shared__ float s_f[3 * NWAVE];
    __shared__ int   s_i[NWAVE];

    const unsigned char* obj_row = g_obj + (size_t)b * NP;
    for (int i = tid; i < CHUNK; i += BLK) s_objc[i] = obj_row[lo + i];
    if (tid < NO * 4) ((float*)s_bcw)[tid] = boxes[(size_t)b * NO * 4 + tid];
    if (tid < NO) {
        // splits cover ascending p ranges: prefer larger v, then smaller idx
        const float* bv = g_bv + ((size_t)b * NO + tid) * SPLIT;
        const int*   bi = g_bi + ((size_t)b * NO + tid) * SPLIT;
        float v = bv[0]; int i = bi[0];
#pragma unroll
        for (int k = 1; k < SPLIT; k++) {
            float v2 = bv[k]; int i2 = bi[k];
            if (v2 > v || (v2 == v && i2 < i)) { v = v2; i = i2; }
        }
        s_bestp[tid] = i;
    }
    for (int i = tid; i < 4096; i += BLK) s_hist[i] = 0u;
    __syncthreads();
    if (tid == 0) {   // forced assignment, ascending o: last o wins
#pragma unroll
        for (int o = 0; o < NO; o++) {
            int bp = s_bestp[o];
            if (bp >= lo && bp < hi) s_objc[bp - lo] = (unsigned char)(0x80 | o);
        }
    }
    __syncthreads();

    float loc_sum = 0.0f, conf_pos = 0.0f, ce_sum = 0.0f; int np = 0;
    const float2* sc2 = (const float2*)(pscores + (size_t)b * NP * 2);
    const float4* pl4 = (const float4*)(plocs  + (size_t)b * NP * 4);
    float* ce_row = g_ce + (size_t)b * NP;
#pragma unroll
    for (int k = 0; k < 9; k++) {
        int p = lo + tid + k * BLK;
        if (p < hi) {
            unsigned m = s_objc[p - lo];
            bool pos = (m & 0x80) != 0;
            float2 sv = sc2[p];
            float mx = fmaxf(sv.x, sv.y);
            float dd = fabsf(sv.x - sv.y);
            float cev = mx + __logf(1.0f + __expf(-dd)) - (pos ? sv.y : sv.x);
            float v = 0.0f;
            if (pos) {
                np++;
                conf_pos += cev;
                int o = m & 15;
                float4 pr = ((const float4*)priors)[p];
                float gx = (s_bcw[o][0] - pr.x) / (pr.z / 10.0f);
                float gy = (s_bcw[o][1] - pr.y) / (pr.w / 10.0f);
                float gw = __logf(s_bcw[o][2] / pr.z) * 5.0f;
                float gh = __logf(s_bcw[o][3] / pr.w) * 5.0f;
                float4 pl = pl4[p];
                loc_sum += fabsf(pl.x - gx) + fabsf(pl.y - gy)
                         + fabsf(pl.z - gw) + fabsf(pl.w - gh);
            } else {
                v = cev;
            }
            ce_row[p] = v;
            ce_sum += v;
            atomicAdd(&s_hist[__float_as_uint(v) >> 19], 1u);
        }
    }
    __syncthreads();

    // merge nonzero bins into the per-row global histogram
    unsigned* gh = g_hist + (size_t)b * 4096;
    for (int i = tid; i < 4096; i += BLK) {
        unsigned h = s_hist[i];
        if (h) atomicAdd(&gh[i], h);
    }

    // chunk partials
    float a = (float)np, c = conf_pos, l = loc_sum, e = ce_sum;
    for (int off = 32; off; off >>= 1) {
        a += __shfl_down(a, off, 64);
        c += __shfl_down(c, off, 64);
        l += __shfl_down(l, off, 64);
        e += __shfl_down(e, off, 64);
    }
    if (lane == 0) { s_f[wv] = a; s_f[NWAVE + wv] = c; s_f[2 * NWAVE + wv] = l; s_i[wv] = __float_as_int(e); }
    __syncthreads();
    if (tid == 0) {
        float sa = 0, sc = 0, sl = 0, se = 0;
#pragma unroll
        for (int w = 0; w < NWAVE; w++) {
            sa += s_f[w]; sc += s_f[NWAVE + w]; sl += s_f[2 * NWAVE + w];
            se += __int_as_float(s_i[w]);
        }
        float* pp = g_part + ((size_t)b * SPLIT + s) * 4;
        pp[0] = sa; pp[1] = sc; pp[2] = sl; pp[3] = se;
    }
}

// Histogram bin selection over 4096 bins (kk-th largest from top); updates kk
// to the rank within the returned bin. HW-verified round 7.
__device__ __forceinline__ int hist_select(unsigned* hist, unsigned* s_part,
                                           unsigned* s_csuf, unsigned* s_sel,
                                           unsigned& kk, int tid, int lane, int wv)
{
    unsigned ps = 0;
#pragma unroll
    for (int i = 0; i < 16; i++) ps += hist[tid * 16 + i];
    s_part[tid] = ps;
    __syncthreads();
    if (wv == 0) {
        unsigned c0 = s_part[4 * lane + 0], c1 = s_part[4 * lane + 1];
        unsigned c2 = s_part[4 * lane + 2], c3 = s_part[4 * lane + 3];
        unsigned g = c0 + c1 + c2 + c3;
        unsigned incl = g;
#pragma unroll
        for (int off = 1; off < 64; off <<= 1) {
            unsigned o = __shfl_down(incl, off, 64);
            if (lane + off < 64) incl += o;
        }
        unsigned excl = incl - g;
        s_csuf[4 * lane + 3] = excl;
        s_csuf[4 * lane + 2] = excl + c3;
        s_csuf[4 * lane + 1] = excl + c3 + c2;
        s_csuf[4 * lane + 0] = excl + c3 + c2 + c1;
    }
    __syncthreads();
    unsigned base = s_csuf[tid];
    if (base < kk && kk <= base + s_part[tid]) {
        unsigned run = base;
        for (int i = 15; i >= 0; i--) {
            unsigned h = hist[tid * 16 + i];
            if (kk <= run + h) { s_sel[0] = (unsigned)(tid * 16 + i); s_sel[1] = kk - run; break; }
            run += h;
        }
    }
    __syncthreads();
    kk = s_sel[1];
    return (int)s_sel[0];
}

// Kernel C: per-row select + final loss pieces. Uses the prefab histogram;
// one row scan gathers boundary-bin candidates to LDS for an exact in-LDS
// radix select. Slow path (candidate overflow) rescans global.
__global__ __launch_bounds__(BLK, 2) void select_kernel(
    const float* __restrict__ g_ce,
    const unsigned* __restrict__ g_hist,
    const float* __restrict__ g_part,
    float* __restrict__ loc_out,
    float* __restrict__ conf_out,
    int*   __restrict__ npos_out)
{
    const int b    = blockIdx.x;
    const int tid  = threadIdx.x;
    const int lane = tid & 63;
    const int wv   = tid >> 6;

    __shared__ unsigned s_hist[4096];
    __shared__ float    s_cand[CAP];
    __shared__ unsigned s_part[256];
    __shared__ unsigned s_csuf[256];
    __shared__ unsigned s_sel[2];
    __shared__ unsigned s_cnt;
    __shared__ float    s_tval;
    __shared__ float    s_f[NWAVE];
    __shared__ int      s_i[NWAVE];

    float npf = 0, cp = 0, loc = 0, cs = 0;
#pragma unroll
    for (int k = 0; k < SPLIT; k++) {
        const float* pp = g_part + ((size_t)b * SPLIT + k) * 4;
        npf += pp[0]; cp += pp[1]; loc += pp[2]; cs += pp[3];
    }
    const int n_pos = (int)(npf + 0.5f);
    const int K = 3 * n_pos;

    if (K >= NP) {
        if (tid == 0) { conf_out[b] = cp + cs; loc_out[b] = loc; npos_out[b] = n_pos; }
        return;
    }

    const unsigned* gh = g_hist + (size_t)b * 4096;
    for (int i = tid; i < 4096; i += BLK) s_hist[i] = gh[i];
    if (tid == 0) s_cnt = 0u;
    __syncthreads();

    unsigned kk = (unsigned)K;
    unsigned b1 = (unsigned)hist_select(s_hist, s_part, s_csuf, s_sel, kk, tid, lane, wv);
    const unsigned kk_bin = kk;            // rank within bin b1
    const unsigned m_total = s_hist[b1];

    // row scan: sum above-bin values, gather bin-b1 candidates
    const float4* row = (const float4*)(g_ce + (size_t)b * NP);
    float shi = 0.0f;
    for (int q = tid; q < NQ; q += BLK) {
        float4 v = row[q];
#pragma unroll
        for (int j = 0; j < 4; j++) {
            float f = (j == 0 ? v.x : j == 1 ? v.y : j == 2 ? v.z : v.w);
            unsigned bin = __float_as_uint(f) >> 19;
            if (bin > b1) shi += f;
            else if (bin == b1) {
                unsigned idx = atomicAdd(&s_cnt, 1u);
                if (idx < CAP) s_cand[idx] = f;
            }
        }
    }
    for (int off = 32; off; off >>= 1) shi += __shfl_down(shi, off, 64);
    if (lane == 0) s_f[wv] = shi;
    __syncthreads();
    shi = 0.0f;
#pragma unroll
    for (int w = 0; w < NWAVE; w++) shi += s_f[w];

    float conf_hn;
    if (m_total <= (unsigned)CAP) {
        // exact radix among candidates on bits [19:0] (bits >=19 shared)
        unsigned prefix = b1 << 19;
        float t = 0.0f;
        bool done = false;
        for (int shift = 16; shift >= 0 && !done; shift -= 4) {
            __syncthreads();
            if (tid < 16) s_part[tid] = 0u;
            __syncthreads();
            unsigned mh = 0xFFFFFFFFu << (shift + 4);
            for (int i = tid; i < (int)m_total; i += BLK) {
                unsigned u = __float_as_uint(s_cand[i]);
                if (((u ^ prefix) & mh) == 0u)
                    atomicAdd(&s_part[(u >> shift) & 15u], 1u);
            }
            __syncthreads();
            int dsel = 15; unsigned cnt;
            for (;; dsel--) { cnt = s_part[dsel]; if (kk <= cnt || dsel == 0) break; kk -= cnt; }
            prefix |= ((unsigned)dsel << shift);
            if (shift > 0 && cnt == 1u) {
                unsigned mh2 = 0xFFFFFFFFu << shift;
                for (int i = tid; i < (int)m_total; i += BLK) {
                    unsigned u = __float_as_uint(s_cand[i]);
                    if (((u ^ prefix) & mh2) == 0u) s_tval = s_cand[i];
                }
                __syncthreads();
                t = s_tval; done = true;
            } else if (shift == 0) {
                t = __uint_as_float(prefix);
            }
        }
        // top-kk_bin within the bin = sum(c > t) + (kk_bin - cnt)*t
        float sg = 0.0f; int cg = 0;
        for (int i = tid; i < (int)m_total; i += BLK) {
            float c = s_cand[i];
            if (c > t) { sg += c; cg++; }
        }
        for (int off = 32; off; off >>= 1) {
            sg += __shfl_down(sg, off, 64);
            cg += __shfl_down(cg, off, 64);
        }
        __syncthreads();
        if (lane == 0) { s_f[wv] = sg; s_i[wv] = cg; }
        __syncthreads();
        sg = 0.0f; cg = 0;
#pragma unroll
        for (int w = 0; w < NWAVE; w++) { sg += s_f[w]; cg += s_i[w]; }
        conf_hn = shi + sg + (float)((int)kk_bin - cg) * t;
    } else {
        // slow path: levels 2/3 over the global row (bits 18:7, then 6:0)
        __syncthreads();
        for (int i = tid; i < 4096; i += BLK) s_hist[i] = 0u;
        __syncthreads();
        for (int q = tid; q < NQ; q += BLK) {
            float4 v = row[q];
#pragma unroll
            for (int j = 0; j < 4; j++) {
                unsigned u = __float_as_uint(j == 0 ? v.x : j == 1 ? v.y : j == 2 ? v.z : v.w);
                if ((u >> 19) == b1) atomicAdd(&s_hist[(u >> 7) & 0xFFFu], 1u);
            }
        }
        __syncthreads();
        unsigned b2 = (unsigned)hist_select(s_hist, s_part, s_csuf, s_sel, kk, tid, lane, wv);
        unsigned p2 = (b1 << 12) | b2;
        __syncthreads();
        for (int i = tid; i < 4096; i += BLK) s_hist[i] = 0u;
        __syncthreads();
        for (int q = tid; q < NQ; q += BLK) {
            float4 v = row[q];
#pragma unroll
            for (int j = 0; j < 4; j++) {
                unsigned u = __float_as_uint(j == 0 ? v.x : j == 1 ? v.y : j == 2 ? v.z : v.w);
                if ((u >> 7) == p2) atomicAdd(&s_hist[u & 0x7Fu], 1u);
            }
        }
        __syncthreads();
        unsigned b3 = (unsigned)hist_select(s_hist, s_part, s_csuf, s_sel, kk, tid, lane, wv);
        float t = __uint_as_float((p2 << 7) | b3);
        float sg = 0.0f; int cg = 0;
        for (int q = tid; q < NQ; q += BLK) {
            float4 v = row[q];
            if (v.x > t) { sg += v.x; cg++; }
            if (v.y > t) { sg += v.y; cg++; }
            if (v.z > t) { sg += v.z; cg++; }
            if (v.w > t) { sg += v.w; cg++; }
        }
        for (int off = 32; off; off >>= 1) {
            sg += __shfl_down(sg, off, 64);
            cg += __shfl_down(cg, off, 64);
        }
        __syncthreads();
        if (lane == 0) { s_f[wv] = sg; s_i[wv] = cg; }
        __syncthreads();
        sg = 0.0f; cg = 0;
#pragma unroll
        for (int w = 0; w < NWAVE; w++) { sg += s_f[w]; cg += s_i[w]; }
        conf_hn = sg + (float)(K - cg) * t;
    }

    if (tid == 0) {
        conf_out[b] = cp + conf_hn;
        loc_out[b]  = loc;
        npos_out[b] = n_pos;
    }
}

// ------------- round-7 loss kernel (mid fallback, needs only g_obj) --------
__global__ __launch_bounds__(BLK, 2) void loss_kernel(
    const float* __restrict__ plocs, const float* __restrict__ pscores,
    const float* __restrict__ boxes, const float* __restrict__ priors,
    const unsigned char* __restrict__ g_obj,
    const float* __restrict__ g_bv, const int* __restrict__ g_bi,
    float* __restrict__ loc_out, float* __restrict__ conf_out,
    int* __restrict__ npos_out)
{
    const int b = blockIdx.x, tid = threadIdx.x, lane = tid & 63, wv = tid >> 6;
    __shared__ __align__(16) float s_ce[NP];
    __shared__ unsigned char s_obj[NP];
    __shared__ unsigned s_hist[4096];
    __shared__ unsigned s_part[256], s_csuf[256], s_sel[2];
    __shared__ float s_bcw[NO][4];
    __shared__ int s_bestp[NO];
    __shared__ float s_tval;
    __shared__ float s_fred[3 * NWAVE]; __shared__ int s_ired[NWAVE];

    const unsigned* objw = (const unsigned*)(g_obj + (size_t)b * NP);
    for (int i = tid; i < NP / 4; i += BLK) ((unsigned*)s_obj)[i] = objw[i];
    if (tid < NO * 4) ((float*)s_bcw)[tid] = boxes[(size_t)b * NO * 4 + tid];
    if (tid < NO) {
        const float* bv = g_bv + ((size_t)b * NO + tid) * SPLIT;
        const int*   bi = g_bi + ((size_t)b * NO + tid) * SPLIT;
        float v = bv[0]; int i = bi[0];
#pragma unroll
        for (int s = 1; s < SPLIT; s++) {
            float v2 = bv[s]; int i2 = bi[s];
            if (v2 > v || (v2 == v && i2 < i)) { v = v2; i = i2; }
        }
        s_bestp[tid] = i;
    }
    __syncthreads();
    if (tid == 0) {
#pragma unroll
        for (int o = 0; o < NO; o++) s_obj[s_bestp[o]] = (unsigned char)(0x80 | o);
    }
    __syncthreads();
    float loc_sum = 0.0f, conf_pos = 0.0f; int np = 0;
    const float2* sc2 = (const float2*)(pscores + (size_t)b * NP * 2);
    const float4* pl4 = (const float4*)(plocs + (size_t)b * NP * 4);
    for (int p = tid; p < NP; p += BLK) {
        unsigned m = s_obj[p]; bool pos = (m & 0x80) != 0;
        float2 s = sc2[p];
        float mx = fmaxf(s.x, s.y), dd = fabsf(s.x - s.y);
        float cev = mx + __logf(1.0f + __expf(-dd)) - (pos ? s.y : s.x);
        if (pos) {
            np++; conf_pos += cev;
            int o = m & 15;
            float4 pr = ((const float4*)priors)[p];
            float gx = (s_bcw[o][0] - pr.x) / (pr.z / 10.0f);
            float gy = (s_bcw[o][1] - pr.y) / (pr.w / 10.0f);
            float gw = __logf(s_bcw[o][2] / pr.z) * 5.0f;
            float gh = __logf(s_bcw[o][3] / pr.w) * 5.0f;
            float4 pl = pl4[p];
            loc_sum += fabsf(pl.x - gx) + fabsf(pl.y - gy) + fabsf(pl.z - gw) + fabsf(pl.w - gh);
            s_ce[p] = 0.0f;
        } else s_ce[p] = cev;
    }
    int npw = np;
    for (int off = 32; off; off >>= 1) npw += __shfl_down(npw, off, 64);
    if (lane == 0) s_ired[wv] = npw;
    __syncthreads();
    int n_pos = 0;
#pragma unroll
    for (int w = 0; w < NWAVE; w++) n_pos += s_ired[w];
    const int K = 3 * n_pos; const bool selAll = (K >= NP);
    float t = 0.0f;
    const float4* ce4 = (const float4*)s_ce;
    if (!selAll) {
        unsigned kk = (unsigned)K;
        for (int i = tid; i < 4096; i += BLK) s_hist[i] = 0u;
        __syncthreads();
        for (int q = tid; q < NQ; q += BLK) {
            float4 v = ce4[q];
            atomicAdd(&s_hist[__float_as_uint(v.x) >> 19], 1u);
            atomicAdd(&s_hist[__float_as_uint(v.y) >> 19], 1u);
            atomicAdd(&s_hist[__float_as_uint(v.z) >> 19], 1u);
            atomicAdd(&s_hist[__float_as_uint(v.w) >> 19], 1u);
        }
        __syncthreads();
        unsigned b1 = (unsigned)hist_select(s_hist, s_part, s_csuf, s_sel, kk, tid, lane, wv);
        __syncthreads();
        for (int i = tid; i < 4096; i += BLK) s_hist[i] = 0u;
        __syncthreads();
        for (int q = tid; q < NQ; q += BLK) {
            float4 v = ce4[q];
#pragma unroll
            for (int j = 0; j < 4; j++) {
                unsigned u = __float_as_uint(j == 0 ? v.x : j == 1 ? v.y : j == 2 ? v.z : v.w);
                if ((u >> 19) == b1) atomicAdd(&s_hist[(u >> 7) & 0xFFFu], 1u);
            }
        }
        __syncthreads();
        unsigned b2 = (unsigned)hist_select(s_hist, s_part, s_csuf, s_sel, kk, tid, lane, wv);
        unsigned p2 = (b1 << 12) | b2;
        __syncthreads();
        for (int i = tid; i < 4096; i += BLK) s_hist[i] = 0u;
        __syncthreads();
        for (int q = tid; q < NQ; q += BLK) {
            float4 v = ce4[q];
#pragma unroll
            for (int j = 0; j < 4; j++) {
                unsigned u = __float_as_uint(j == 0 ? v.x : j == 1 ? v.y : j == 2 ? v.z : v.w);
                if ((u >> 7) == p2) atomicAdd(&s_hist[u & 0x7Fu], 1u);
            }
        }
        __syncthreads();
        unsigned b3 = (unsigned)hist_select(s_hist, s_part, s_csuf, s_sel, kk, tid, lane, wv);
        t = __uint_as_float((p2 << 7) | b3);
    }
    float sgt = 0.0f; int cgt = 0;
    for (int q = tid; q < NQ; q += BLK) {
        float4 v = ce4[q];
        if (selAll || v.x > t) { sgt += v.x; cgt++; }
        if (selAll || v.y > t) { sgt += v.y; cgt++; }
        if (selAll || v.z > t) { sgt += v.z; cgt++; }
        if (selAll || v.w > t) { sgt += v.w; cgt++; }
    }
    float a = sgt, c = conf_pos, l = loc_sum; int g = cgt;
    for (int off = 32; off; off >>= 1) {
        a += __shfl_down(a, off, 64); c += __shfl_down(c, off, 64);
        l += __shfl_down(l, off, 64); g += __shfl_down(g, off, 64);
    }
    __syncthreads();
    if (lane == 0) { s_fred[wv] = a; s_fred[NWAVE + wv] = c; s_fred[2 * NWAVE + wv] = l; s_ired[wv] = g; }
    __syncthreads();
    if (tid == 0) {
        float sa = 0, sc = 0, sl = 0; int sg = 0;
#pragma unroll
        for (int w = 0; w < NWAVE; w++) { sa += s_fred[w]; sc += s_fred[NWAVE + w]; sl += s_fred[2 * NWAVE + w]; sg += s_ired[w]; }
        float conf_hn = selAll ? sa : (sa + (float)(K - sg) * t);
        conf_out[b] = sc + conf_hn; loc_out[b] = sl; npos_out[b] = n_pos;
    }
}

__global__ __launch_bounds__(256) void mbox_finalize_kernel(
    const float* __restrict__ loc_in, const float* __restrict__ conf_in,
    const int* __restrict__ npos_in, int B, float* __restrict__ out)
{
    __shared__ float sl[4], sc[4];
    __shared__ int si[4];
    int tid = threadIdx.x, lane = tid & 63, wv = tid >> 6;
    float l = 0.0f, c = 0.0f; int n = 0;
    for (int i = tid; i < B; i += 256) { l += loc_in[i]; c += conf_in[i]; n += npos_in[i]; }
    for (int off = 32; off; off >>= 1) {
        l += __shfl_down(l, off, 64);
        c += __shfl_down(c, off, 64);
        n += __shfl_down(n, off, 64);
    }
    if (lane == 0) { sl[wv] = l; sc[wv] = c; si[wv] = n; }
    __syncthreads();
    if (tid == 0) {
        float tl = sl[0] + sl[1] + sl[2] + sl[3];
        float tc = sc[0] + sc[1] + sc[2] + sc[3];
        int tn = si[0] + si[1] + si[2] + si[3];
        float fn = (float)tn;
        out[0] = tc / fn + tl / (fn * 4.0f);
    }
}

extern "C" void kernel_launch(void* const* d_in, const int* in_sizes, int n_in,
                              void* d_out, int out_size, void* d_ws, size_t ws_size,
                              hipStream_t stream) {
    const float* plocs   = (const float*)d_in[0];
    const float* pscores = (const float*)d_in[1];
    const float* boxes   = (const float*)d_in[2];
    const float* priors  = (const float*)d_in[3];
    const int B = in_sizes[0] / (NP * 4);

    // full layout: loc,conf,np | g_bv,g_bi | g_part | g_hist | g_ce | g_obj
    float* loc_ws  = (float*)d_ws;
    float* conf_ws = loc_ws + B;
    int*   np_ws   = (int*)(conf_ws + B);
    float* g_bv    = (float*)(np_ws + B);
    int*   g_bi    = (int*)(g_bv + (size_t)B * NO * SPLIT);
    float* g_part  = (float*)(g_bi + (size_t)B * NO * SPLIT);
    unsigned* g_hist = (unsigned*)(g_part + (size_t)B * SPLIT * 4);
    float* g_ce    = (float*)(g_hist + (size_t)B * 4096);
    unsigned char* g_obj = (unsigned char*)(g_ce + (size_t)B * NP);
    size_t need_full = (size_t)((char*)(g_obj + (size_t)B * NP) - (char*)d_ws);

    if (ws_size >= need_full) {
        int n4 = B * 4096 / 4;
        zero_hist_kernel<<<(n4 + BLK - 1) / BLK, BLK, 0, stream>>>((uint4*)g_hist, n4);
        match_kernel<<<dim3(B, SPLIT), BLK, 0, stream>>>(boxes, priors, g_obj, g_bv, g_bi);
        ce_kernel<<<dim3(B, SPLIT), BLK, 0, stream>>>(plocs, pscores, boxes, priors,
                                                      g_obj, g_bv, g_bi, g_ce, g_hist, g_part);
        select_kernel<<<B, BLK, 0, stream>>>(g_ce, g_hist, g_part,
                                             loc_ws, conf_ws, np_ws);
    } else {
        // mid layout: loc,conf,np | g_bv,g_bi | g_obj
        unsigned char* g_obj2 = (unsigned char*)(g_bi + (size_t)B * NO * SPLIT);
        size_t need_mid = (size_t)((char*)(g_obj2 + (size_t)B * NP) - (char*)d_ws);
        if (ws_size >= need_mid) {
            match_kernel<<<dim3(B, SPLIT), BLK, 0, stream>>>(boxes, priors, g_obj2, g_bv, g_bi);
            loss_kernel<<<B, BLK, 0, stream>>>(plocs, pscores, boxes, priors,
                                               g_obj2, g_bv, g_bi, loc_ws, conf_ws, np_ws);
        }
    }
    mbox_finalize_kernel<<<1, 256, 0, stream>>>(loc_ws, conf_ws, np_ws, B, (float*)d_out);
}